// Round 13
// baseline (631.672 us; speedup 1.0000x reference)
//
#include <hip/hip_runtime.h>
#include <hip/hip_cooperative_groups.h>
#include <math.h>

namespace cg = cooperative_groups;

#define NNODES 100000
#define NEDGES 3200000
#define NB 391        // buckets of 256 nodes
#define PB 512        // partition blocks for bucket passes
#define CHUNK 6250    // NEDGES / PB

typedef __attribute__((ext_vector_type(4))) float f32x4;
typedef __attribute__((ext_vector_type(2))) float f32x2;
typedef __attribute__((ext_vector_type(8))) short bf16x8;

__device__ __forceinline__ float bf2f(ushort u) {
    union { unsigned u; float f; } v; v.u = ((unsigned)u) << 16; return v.f;
}
__device__ __forceinline__ ushort f2bf(float f) {
    union { float f; unsigned u; } v; v.f = f;
    unsigned r = v.u + 0x7FFFu + ((v.u >> 16) & 1u);
    return (ushort)(r >> 16);
}

// pack two f32 into one u32 of 2 bf16 (truncation) — single v_perm_b32
__device__ __forceinline__ unsigned pack_bf2(float f0, float f1) {
    union { float f; unsigned u; } a, b; a.f = f0; b.f = f1;
#if __has_builtin(__builtin_amdgcn_perm)
    return __builtin_amdgcn_perm(b.u, a.u, 0x07060302u);
#else
    return (b.u & 0xFFFF0000u) | (a.u >> 16);
#endif
}

// ---------------- fp8 e4m3 helpers ----------------
#if __has_builtin(__builtin_amdgcn_cvt_pk_fp8_f32) && __has_builtin(__builtin_amdgcn_cvt_pk_f32_fp8)
#define FP8_HW 1
#else
#define FP8_HW 0
#endif

__device__ __forceinline__ unsigned fp8enc_sw(float f) {
    union { float f; unsigned u; } v; v.f = f;
    unsigned sign = v.u >> 31;
    float a = fabsf(f);
    if (a >= 448.0f) return (sign << 7) | 0x7E;
    if (a < 0.0009765625f) return sign << 7;
    unsigned u = v.u & 0x7FFFFFFFu;
    u += 0x7FFFFu + ((u >> 20) & 1u);
    int e2 = (int)(u >> 23) - 127;
    if (e2 < -6) {
        int m = (int)(a * 512.0f + 0.5f); if (m > 7) m = 7;
        return (sign << 7) | (unsigned)m;
    }
    if (e2 > 8) return (sign << 7) | 0x7E;
    unsigned mant = (u >> 20) & 7u;
    return (sign << 7) | ((unsigned)(e2 + 7) << 3) | mant;
}
__device__ __forceinline__ float fp8dec_sw(unsigned b) {
    unsigned s = b >> 7, e = (b >> 3) & 0xF, m = b & 7;
    float v;
    if (e == 0) v = (float)m * 0.001953125f;
    else { union { unsigned u; float f; } x; x.u = ((e + 120u) << 23) | (m << 20); v = x.f; }
    return s ? -v : v;
}

__device__ __forceinline__ unsigned char f2fp8(float f) {
#if FP8_HW
    return (unsigned char)(__builtin_amdgcn_cvt_pk_fp8_f32(f, 0.f, 0, false) & 0xFF);
#else
    return (unsigned char)fp8enc_sw(f);
#endif
}
// packed accumulate: 2 cvt + 2 pk_add per 4 features
__device__ __forceinline__ void fp8x4_acc2(unsigned w, f32x2& a01, f32x2& a23) {
#if FP8_HW
    a01 += __builtin_amdgcn_cvt_pk_f32_fp8((int)w, false);
    a23 += __builtin_amdgcn_cvt_pk_f32_fp8((int)w, true);
#else
    a01[0] += fp8dec_sw(w & 0xFF); a01[1] += fp8dec_sw((w >> 8) & 0xFF);
    a23[0] += fp8dec_sw((w >> 16) & 0xFF); a23[1] += fp8dec_sw(w >> 24);
#endif
}

// ---------------- cooperative fused CSR build + weight conversion ----------------
// Phases: [hist || conv_weights] -> gsync -> scan_buckets -> gsync -> scan_btotal
//         -> gsync -> scatter -> gsync -> finalize
__launch_bounds__(256)
__global__ void csr_build_coop(const int* __restrict__ src, const int* __restrict__ dst, int e,
                               int* __restrict__ hist, int* __restrict__ btotal,
                               int* __restrict__ bstart, unsigned* __restrict__ bucketed,
                               float* __restrict__ dinv, int* __restrict__ rowptr,
                               int* __restrict__ esrc, int n,
                               const float* __restrict__ W1, ushort* __restrict__ W1t,
                               const float* __restrict__ W2, unsigned char* __restrict__ W2t,
                               const float* __restrict__ W3, unsigned char* __restrict__ W3t) {
    cg::grid_group grid = cg::this_grid();
    __shared__ int shA[NB];
    __shared__ int shB[256];
    __shared__ int shC[256];
    const int b = blockIdx.x, t = threadIdx.x;

    // ---- P1: per-partition histogram of dst>>8, plus weight conversion ----
    for (int j = t; j < NB; j += 256) shA[j] = 0;
    __syncthreads();
    {
        const int lo = b * CHUNK;
        int hi = lo + CHUNK; if (hi > e) hi = e;
        for (int i = lo + t; i < hi; i += 256)
            atomicAdd(&shA[dst[i] >> 8], 1);
    }
    // weight conversion interleaved (independent work)
    {
        const int stride = PB * 256;
        for (int idx = b * 256 + t; idx < 256 * 512 + 64 * 256 + 16 * 64; idx += stride) {
            if (idx < 256 * 512) {
                int nn = idx / 512, k = idx % 512;
                W1t[idx] = f2bf(W1[(size_t)k * 256 + nn]);
            } else if (idx < 256 * 512 + 64 * 256) {
                int r = idx - 256 * 512;
                int nn = r / 256, k = r % 256;
                W2t[r] = f2fp8(W2[(size_t)k * 64 + nn]);
            } else {
                int r = idx - 256 * 512 - 64 * 256;
                int nn = r / 64, k = r % 64;
                W3t[r] = (nn < 10) ? f2fp8(W3[(size_t)k * 10 + nn]) : (unsigned char)0;
            }
        }
    }
    __syncthreads();
    for (int j = t; j < NB; j += 256) hist[b * NB + j] = shA[j];

    grid.sync();

    // ---- P2: per-bucket exclusive scan over the PB partitions ----
    if (b < NB) {
        const int j = b;
        int v0 = hist[(2 * t) * NB + j];
        int v1 = hist[(2 * t + 1) * NB + j];
        int p = v0 + v1;
        shB[t] = p;
        __syncthreads();
        for (int off = 1; off < 256; off <<= 1) {
            int u = (t >= off) ? shB[t - off] : 0;
            __syncthreads();
            shB[t] += u;
            __syncthreads();
        }
        int excl = shB[t] - p;
        hist[(2 * t) * NB + j] = excl;
        hist[(2 * t + 1) * NB + j] = excl + v0;
        if (t == 255) btotal[j] = shB[255];
    }

    grid.sync();

    // ---- P3: exclusive scan of bucket totals -> bstart (block 0, 2 per thread) ----
    if (b == 0) {
        const int i0 = 2 * t, i1 = 2 * t + 1;
        int v0 = (i0 < NB) ? btotal[i0] : 0;
        int v1 = (i1 < NB) ? btotal[i1] : 0;
        int p = v0 + v1;
        shB[t] = p;
        __syncthreads();
        for (int off = 1; off < 256; off <<= 1) {
            int u = (t >= off) ? shB[t - off] : 0;
            __syncthreads();
            shB[t] += u;
            __syncthreads();
        }
        int excl = shB[t] - p;
        if (i0 < NB) bstart[i0] = excl;
        if (i1 < NB) bstart[i1] = excl + v0;
        if (t == 0) bstart[NB] = e;
    }

    grid.sync();

    // ---- P4: scatter edges into bucket-grouped array ----
    {
        for (int j = t; j < NB; j += 256) shA[j] = bstart[j] + hist[b * NB + j];
        __syncthreads();
        const int lo = b * CHUNK;
        int hi = lo + CHUNK; if (hi > e) hi = e;
        for (int i = lo + t; i < hi; i += 256) {
            int d = dst[i];
            int j = d >> 8;
            int p = atomicAdd(&shA[j], 1);
            bucketed[p] = (unsigned)src[i] | ((unsigned)(d & 255) << 24);
        }
    }

    grid.sync();

    // ---- P5: per-bucket histogram + within-bucket scan -> dinv/rowptr, then CSR fill ----
    if (b < NB) {
        const int j = b;
        shA[t] = 0;
        __syncthreads();
        const int lo = bstart[j], hi = bstart[j + 1];
        for (int i = lo + t; i < hi; i += 256)
            atomicAdd(&shA[bucketed[i] >> 24], 1);
        __syncthreads();
        const int c = shA[t] + 1;  // deg + self loop
        shB[t] = c;
        __syncthreads();
        for (int off = 1; off < 256; off <<= 1) {
            int u = (t >= off) ? shB[t - off] : 0;
            __syncthreads();
            shB[t] += u;
            __syncthreads();
        }
        const int excl = shB[t] - c;
        const int base = j << 8;
        const int node = base + t;
        const int myrp = bstart[j] + base + excl;
        shC[t] = myrp;
        if (node < n) {
            dinv[node] = rsqrtf((float)c);
            rowptr[node] = myrp;
            esrc[myrp] = node;  // self loop at slot 0
        }
        if (j == 0 && t == 0) rowptr[n] = e + n;
        shA[t] = 0;
        __syncthreads();
        for (int i = lo + t; i < hi; i += 256) {
            unsigned ed = bucketed[i];
            int l = ed >> 24;
            int off = atomicAdd(&shA[l], 1);
            esrc[shC[l] + 1 + off] = (int)(ed & 0xFFFFFFu);
        }
    }
}

// ---------------- GEMM layer 1: f32 A staged directly (swizzled), fp8 output ----------------
template <int BM, int BN, int BK, int WM, int WN>
__launch_bounds__(WM* WN * 64)
__global__ void gemm_f32a(const float* __restrict__ A, const ushort* __restrict__ Bt,
                          const float* __restrict__ dinv, unsigned char* __restrict__ Cout,
                          int M, int N, int K) {
    constexpr int NT = WM * WN * 64;
    __shared__ __align__(16) float Asf[BM][BK];
    __shared__ __align__(16) ushort Bs[BN][BK];
    const int tid = threadIdx.x;
    const int wid = tid >> 6, lane = tid & 63;
    const int wr = wid / WN, wc = wid % WN;
    constexpr int TM = BM / WM, TN = BN / WN;
    constexpr int FM = TM / 16, FN = TN / 16;
    const int m0 = blockIdx.y * BM, n0 = blockIdx.x * BN;
    const int ln = lane & 15, ks4 = (lane >> 4) * 2;

    f32x4 acc[FM][FN] = {};

    constexpr int CPRA = BK / 4;
    constexpr int ACH = BM * CPRA;
    constexpr int CPRB = BK / 8;
    constexpr int BCH = BN * CPRB;

    for (int k0 = 0; k0 < K; k0 += BK) {
        #pragma unroll
        for (int it = 0; it < ACH / NT; ++it) {
            int c = it * NT + tid;
            int row = c >> 3, chs = c & 7;
            int gch = chs ^ (row & 7);
            int gm = m0 + row; if (gm >= M) gm = M - 1;
            const float* gp = &A[(size_t)gm * K + k0 + gch * 4];
            __builtin_amdgcn_global_load_lds(
                (const __attribute__((address_space(1))) void*)gp,
                (__attribute__((address_space(3))) void*)((char*)&Asf[0][0] + c * 16),
                16, 0, 0);
        }
        #pragma unroll
        for (int it = 0; it < BCH / NT; ++it) {
            int c = it * NT + tid;
            int row = c / CPRB, ch = c % CPRB;
            const ushort* gp = &Bt[(size_t)(n0 + row) * K + k0 + ch * 8];
            __builtin_amdgcn_global_load_lds(
                (const __attribute__((address_space(1))) void*)gp,
                (__attribute__((address_space(3))) void*)((char*)&Bs[0][0] + c * 16),
                16, 0, 0);
        }
        __syncthreads();

        bf16x8 af[FM], bfr[FN];
        #pragma unroll
        for (int mi = 0; mi < FM; ++mi) {
            int r = wr * TM + mi * 16 + ln;
            const char* rowp = (const char*)&Asf[0][0] + r * (BK * 4);
            float4 a0 = *(const float4*)(rowp + ((ks4 ^ (r & 7)) * 16));
            float4 a1 = *(const float4*)(rowp + (((ks4 + 1) ^ (r & 7)) * 16));
            union { unsigned w[4]; bf16x8 v; } u;
            u.w[0] = pack_bf2(a0.x, a0.y);
            u.w[1] = pack_bf2(a0.z, a0.w);
            u.w[2] = pack_bf2(a1.x, a1.y);
            u.w[3] = pack_bf2(a1.z, a1.w);
            af[mi] = u.v;
        }
        const int ks = (lane >> 4) * 8;
        #pragma unroll
        for (int nj = 0; nj < FN; ++nj)
            bfr[nj] = *(const bf16x8*)&Bs[wc * TN + nj * 16 + ln][ks];
        #pragma unroll
        for (int mi = 0; mi < FM; ++mi)
            #pragma unroll
            for (int nj = 0; nj < FN; ++nj)
                acc[mi][nj] = __builtin_amdgcn_mfma_f32_16x16x32_bf16(af[mi], bfr[nj], acc[mi][nj], 0, 0, 0);
        __syncthreads();
    }

    const int rbase = (lane >> 4) * 4;
    #pragma unroll
    for (int mi = 0; mi < FM; ++mi) {
        #pragma unroll
        for (int r = 0; r < 4; ++r) {
            int gm = m0 + wr * TM + mi * 16 + rbase + r;
            if (gm >= M) continue;
            float d = dinv[gm];
            #pragma unroll
            for (int nj = 0; nj < FN; ++nj) {
                int gn = n0 + wc * TN + nj * 16 + ln;
                Cout[(size_t)gm * N + gn] = f2fp8(acc[mi][nj][r] * d);
            }
        }
    }
}

// ---------------- fp8 MFMA GEMM (layers 2-3): A fp8 [M][K], Bt fp8 [N][K] ----------------
// OUTK: 0 = bf16, 2 = fp8
template <int BM, int BN, int BK, int WM, int WN, int OUTK>
__launch_bounds__(WM* WN * 64)
__global__ void gemm_fp8(const unsigned char* __restrict__ A, const unsigned char* __restrict__ Bt,
                         const float* __restrict__ dinv, void* __restrict__ Cout,
                         int M, int N, int K) {
    constexpr int NT = WM * WN * 64;
    __shared__ __align__(16) unsigned char As[BM][BK];
    __shared__ __align__(16) unsigned char Bs[BN][BK];
    const int tid = threadIdx.x;
    const int wid = tid >> 6, lane = tid & 63;
    const int wr = wid / WN, wc = wid % WN;
    constexpr int TM = BM / WM, TN = BN / WN;
    constexpr int FM = TM / 16, FN = TN / 16;
    const int m0 = blockIdx.y * BM, n0 = blockIdx.x * BN;
    const int ln = lane & 15;

    f32x4 acc[FM][FN] = {};

    constexpr int CPR = BK / 16;
    constexpr int ACH = BM * CPR;
    constexpr int BCH = BN * CPR;

    for (int k0 = 0; k0 < K; k0 += BK) {
        #pragma unroll
        for (int it = 0; it < (ACH + NT - 1) / NT; ++it) {
            int c = it * NT + tid;
            if ((ACH % NT == 0) || (c < ACH)) {
                int row = c / CPR, ch = c % CPR;
                int gm = m0 + row; if (gm >= M) gm = M - 1;
                const unsigned char* gp = &A[(size_t)gm * K + k0 + ch * 16];
                __builtin_amdgcn_global_load_lds(
                    (const __attribute__((address_space(1))) void*)gp,
                    (__attribute__((address_space(3))) void*)((char*)&As[0][0] + c * 16),
                    16, 0, 0);
            }
        }
        #pragma unroll
        for (int it = 0; it < (BCH + NT - 1) / NT; ++it) {
            int c = it * NT + tid;
            if ((BCH % NT == 0) || (c < BCH)) {
                int row = c / CPR, ch = c % CPR;
                const unsigned char* gp = &Bt[(size_t)(n0 + row) * K + k0 + ch * 16];
                __builtin_amdgcn_global_load_lds(
                    (const __attribute__((address_space(1))) void*)gp,
                    (__attribute__((address_space(3))) void*)((char*)&Bs[0][0] + c * 16),
                    16, 0, 0);
            }
        }
        __syncthreads();

        long af[FM], bfr[FN];
        #pragma unroll
        for (int mi = 0; mi < FM; ++mi)
            af[mi] = ((const long*)&As[0][0])[(wr * TM + mi * 16 + ln) * (BK / 8) + (lane >> 4)];
        #pragma unroll
        for (int nj = 0; nj < FN; ++nj)
            bfr[nj] = ((const long*)&Bs[0][0])[(wc * TN + nj * 16 + ln) * (BK / 8) + (lane >> 4)];
        #pragma unroll
        for (int mi = 0; mi < FM; ++mi)
            #pragma unroll
            for (int nj = 0; nj < FN; ++nj)
                acc[mi][nj] = __builtin_amdgcn_mfma_f32_16x16x32_fp8_fp8(af[mi], bfr[nj], acc[mi][nj], 0, 0, 0);
        __syncthreads();
    }

    const int rbase = (lane >> 4) * 4;
    #pragma unroll
    for (int mi = 0; mi < FM; ++mi) {
        #pragma unroll
        for (int r = 0; r < 4; ++r) {
            int gm = m0 + wr * TM + mi * 16 + rbase + r;
            if (gm >= M) continue;
            float d = dinv[gm];
            #pragma unroll
            for (int nj = 0; nj < FN; ++nj) {
                int gn = n0 + wc * TN + nj * 16 + ln;
                float v = acc[mi][nj][r] * d;
                if (OUTK == 0) ((ushort*)Cout)[(size_t)gm * N + gn] = f2bf(v);
                else           ((unsigned char*)Cout)[(size_t)gm * N + gn] = f2fp8(v);
            }
        }
    }
}

// ---------------- layer-1 aggregation: fp8 rows (256 B), wave/node, 8-edge ILP, fp8 out ----------------
__global__ void agg1_fp8(const unsigned* __restrict__ h, const int* __restrict__ rowptr,
                         const int* __restrict__ esrc, const float* __restrict__ dinv,
                         const float* __restrict__ bias, unsigned char* __restrict__ out, int n) {
    const int wid = threadIdx.x >> 6, lane = threadIdx.x & 63;
    const int i = blockIdx.x * 4 + wid;
    if (i >= n) return;
    const int lo = rowptr[i], hi = rowptr[i + 1];
    f32x2 a01 = {0.f, 0.f}, a23 = {0.f, 0.f};
    int e = lo;
    for (; e + 7 < hi; e += 8) {
        int s[8];
        unsigned w[8];
        #pragma unroll
        for (int q = 0; q < 8; ++q) s[q] = esrc[e + q];
        #pragma unroll
        for (int q = 0; q < 8; ++q) w[q] = h[(size_t)s[q] * 64 + lane];
        #pragma unroll
        for (int q = 0; q < 8; ++q) fp8x4_acc2(w[q], a01, a23);
    }
    for (; e < hi; ++e)
        fp8x4_acc2(h[(size_t)esrc[e] * 64 + lane], a01, a23);

    float d = dinv[i];
    const int f0 = lane * 4;
    float4 b = *(const float4*)&bias[f0];
    uchar4 o;
    o.x = f2fp8(fmaxf(a01[0] * d + b.x, 0.f));
    o.y = f2fp8(fmaxf(a01[1] * d + b.y, 0.f));
    o.z = f2fp8(fmaxf(a23[0] * d + b.z, 0.f));
    o.w = f2fp8(fmaxf(a23[1] * d + b.w, 0.f));
    *(uchar4*)&out[(size_t)i * 256 + f0] = o;
}

// ---------------- layer-2 aggregation: fp8 rows (64 B), 16 lanes/node, 8-edge ILP ----------------
__global__ void agg2_fp8(const unsigned* __restrict__ h, const int* __restrict__ rowptr,
                         const int* __restrict__ esrc, const float* __restrict__ dinv,
                         const float* __restrict__ bias, unsigned char* __restrict__ out, int n) {
    const int g = threadIdx.x >> 4, j = threadIdx.x & 15;
    const int i = blockIdx.x * 16 + g;
    if (i >= n) return;
    const int lo = rowptr[i], hi = rowptr[i + 1];
    f32x2 a01 = {0.f, 0.f}, a23 = {0.f, 0.f};
    int e = lo;
    for (; e + 7 < hi; e += 8) {
        int s[8];
        unsigned w[8];
        #pragma unroll
        for (int q = 0; q < 8; ++q) s[q] = esrc[e + q];
        #pragma unroll
        for (int q = 0; q < 8; ++q) w[q] = h[(size_t)s[q] * 16 + j];
        #pragma unroll
        for (int q = 0; q < 8; ++q) fp8x4_acc2(w[q], a01, a23);
    }
    for (; e < hi; ++e)
        fp8x4_acc2(h[(size_t)esrc[e] * 16 + j], a01, a23);

    float d = dinv[i];
    const int f0 = j * 4;
    float4 b = *(const float4*)&bias[f0];
    uchar4 o;
    o.x = f2fp8(fmaxf(a01[0] * d + b.x, 0.f));
    o.y = f2fp8(fmaxf(a01[1] * d + b.y, 0.f));
    o.z = f2fp8(fmaxf(a23[0] * d + b.z, 0.f));
    o.w = f2fp8(fmaxf(a23[1] * d + b.w, 0.f));
    *(uchar4*)&out[(size_t)i * 64 + f0] = o;
}

// ---------------- layer-3: bf16 rows (32 B), 8 lanes/node, fused log_softmax ----------------
__global__ void agg3_logsoftmax(const ushort* __restrict__ h3, const int* __restrict__ rowptr,
                                const int* __restrict__ esrc, const float* __restrict__ dinv,
                                const float* __restrict__ bias, float* __restrict__ out, int n) {
    const int g = threadIdx.x >> 3, j = threadIdx.x & 7;
    const int i = blockIdx.x * 32 + g;
    if (i >= n) return;
    const int lo = rowptr[i], hi = rowptr[i + 1];
    float a0 = 0.f, a1 = 0.f;
    int e = lo;
    for (; e + 3 < hi; e += 4) {
        int s0 = esrc[e], s1 = esrc[e + 1], s2 = esrc[e + 2], s3 = esrc[e + 3];
        unsigned w0 = *(const unsigned*)&h3[(size_t)s0 * 16 + 2 * j];
        unsigned w1 = *(const unsigned*)&h3[(size_t)s1 * 16 + 2 * j];
        unsigned w2 = *(const unsigned*)&h3[(size_t)s2 * 16 + 2 * j];
        unsigned w3 = *(const unsigned*)&h3[(size_t)s3 * 16 + 2 * j];
        a0 += bf2f((ushort)(w0 & 0xFFFF)) + bf2f((ushort)(w1 & 0xFFFF))
            + bf2f((ushort)(w2 & 0xFFFF)) + bf2f((ushort)(w3 & 0xFFFF));
        a1 += bf2f((ushort)(w0 >> 16)) + bf2f((ushort)(w1 >> 16))
            + bf2f((ushort)(w2 >> 16)) + bf2f((ushort)(w3 >> 16));
    }
    for (; e < hi; ++e) {
        unsigned w = *(const unsigned*)&h3[(size_t)esrc[e] * 16 + 2 * j];
        a0 += bf2f((ushort)(w & 0xFFFF));
        a1 += bf2f((ushort)(w >> 16));
    }
    const int f0 = 2 * j;
    float d = dinv[i];
    float v0 = (f0 < 10) ? (a0 * d + bias[f0]) : -INFINITY;
    float v1 = (f0 + 1 < 10) ? (a1 * d + bias[f0 + 1]) : -INFINITY;
    float m = fmaxf(v0, v1);
    #pragma unroll
    for (int off = 1; off < 8; off <<= 1) m = fmaxf(m, __shfl_xor(m, off, 8));
    float ex = ((f0 < 10) ? expf(v0 - m) : 0.f) + ((f0 + 1 < 10) ? expf(v1 - m) : 0.f);
    #pragma unroll
    for (int off = 1; off < 8; off <<= 1) ex += __shfl_xor(ex, off, 8);
    float ls = logf(ex);
    if (f0 < 10)     out[(size_t)i * 10 + f0] = v0 - m - ls;
    if (f0 + 1 < 10) out[(size_t)i * 10 + f0 + 1] = v1 - m - ls;
}

extern "C" void kernel_launch(void* const* d_in, const int* in_sizes, int n_in,
                              void* d_out, int out_size, void* d_ws, size_t ws_size,
                              hipStream_t stream) {
    const int N = NNODES, E = NEDGES;
    const float* x  = (const float*)d_in[0];
    const int*   ei = (const int*)d_in[1];
    const float* W1 = (const float*)d_in[2];
    const float* b1 = (const float*)d_in[3];
    const float* W2 = (const float*)d_in[4];
    const float* b2 = (const float*)d_in[5];
    const float* W3 = (const float*)d_in[6];
    const float* b3 = (const float*)d_in[7];
    float* out = (float*)d_out;
    const int* src = ei;
    const int* dst = ei + E;

    char* ws = (char*)d_ws;
    size_t off = 0;
    auto alloc = [&](size_t bytes) -> void* {
        void* p = ws + off;
        off = (off + bytes + 255) & ~(size_t)255;
        return p;
    };
    float* dinv   = (float*)alloc((size_t)N * 4);
    int*   rowptr = (int*)alloc((size_t)(N + 1) * 4);
    int*   btotal = (int*)alloc((size_t)NB * 4);
    int*   bstart = (int*)alloc((size_t)(NB + 1) * 4);
    int*   esrc   = (int*)alloc((size_t)(E + N) * 4);
    ushort* W1t   = (ushort*)alloc((size_t)256 * 512 * 2);
    unsigned char* W2t8 = (unsigned char*)alloc((size_t)64 * 256);
    unsigned char* W3t8 = (unsigned char*)alloc((size_t)16 * 64);
    ushort* h3b   = (ushort*)alloc((size_t)N * 16 * 2);
    ushort* buf1  = (ushort*)alloc((size_t)N * 256 * 2);
    ushort* buf2  = (ushort*)alloc((size_t)N * 256 * 2);
    int*   hist   = (int*)buf1;                    // dead before gemm1 writes buf1
    unsigned* bucketed = (unsigned*)buf2;          // dead before agg1 writes buf2
    unsigned char* h1fp8 = (unsigned char*)buf1;   // gemm1 out [N][256B]
    unsigned char* a1fp8 = (unsigned char*)buf2;   // agg1 out  [N][256B] (bucketed dead)
    unsigned char* h2fp8 = (unsigned char*)buf1;   // gemm2 out [N][64B]  (h1fp8 dead)
    unsigned char* a2fp8 = (unsigned char*)buf2;   // agg2 out  [N][64B]  (a1fp8 dead)

    // fused CSR build + weight conversion (cooperative, grid-wide syncs between phases)
    {
        int e_arg = E, n_arg = N;
        void* args[] = {
            (void*)&src, (void*)&dst, (void*)&e_arg,
            (void*)&hist, (void*)&btotal, (void*)&bstart, (void*)&bucketed,
            (void*)&dinv, (void*)&rowptr, (void*)&esrc, (void*)&n_arg,
            (void*)&W1, (void*)&W1t, (void*)&W2, (void*)&W2t8, (void*)&W3, (void*)&W3t8
        };
        hipLaunchCooperativeKernel((const void*)csr_build_coop, dim3(PB), dim3(256),
                                   args, 0, stream);
    }

    const int MB = (N + 127) / 128;

    // Layer 1: f32-A gemm -> fp8 h1 ; fp8 gather -> fp8 a1 [N][256B]
    gemm_f32a<128, 256, 32, 2, 4><<<dim3(1, MB), 512, 0, stream>>>(x, W1t, dinv, h1fp8, N, 256, 512);
    agg1_fp8<<<(N + 3) / 4, 256, 0, stream>>>((const unsigned*)h1fp8, rowptr, esrc, dinv, b1, a1fp8, N);

    // Layer 2: fp8 gemm -> fp8 h2 [N][64B] ; fp8 gather -> fp8 a2 [N][64B]
    gemm_fp8<128, 64, 32, 2, 2, 2><<<dim3(1, MB), 256, 0, stream>>>(a1fp8, W2t8, dinv, h2fp8, N, 64, 256);
    agg2_fp8<<<(N + 15) / 16, 256, 0, stream>>>((const unsigned*)h2fp8, rowptr, esrc, dinv, b2, a2fp8, N);

    // Layer 3: fp8 gemm -> bf16 h3 [N][16] ; gather + fused log_softmax -> out
    gemm_fp8<128, 16, 32, 4, 1, 0><<<dim3(1, MB), 256, 0, stream>>>(a2fp8, W3t8, dinv, h3b, N, 16, 64);
    agg3_logsoftmax<<<(N + 31) / 32, 256, 0, stream>>>(h3b, rowptr, esrc, dinv, b3, out, N);
}

// Round 14
// 373.611 us; speedup vs baseline: 1.6907x; 1.6907x over previous
//
#include <hip/hip_runtime.h>
#include <math.h>

#define NNODES 100000
#define NEDGES 3200000
#define NB 391        // buckets of 256 nodes
#define PB 512        // partition blocks for bucket passes
#define CHUNK 6250    // NEDGES / PB

typedef __attribute__((ext_vector_type(4))) float f32x4;
typedef __attribute__((ext_vector_type(2))) float f32x2;
typedef __attribute__((ext_vector_type(8))) short bf16x8;

__device__ __forceinline__ float bf2f(ushort u) {
    union { unsigned u; float f; } v; v.u = ((unsigned)u) << 16; return v.f;
}
__device__ __forceinline__ ushort f2bf(float f) {
    union { float f; unsigned u; } v; v.f = f;
    unsigned r = v.u + 0x7FFFu + ((v.u >> 16) & 1u);
    return (ushort)(r >> 16);
}

// pack two f32 into one u32 of 2 bf16 (truncation) — single v_perm_b32
__device__ __forceinline__ unsigned pack_bf2(float f0, float f1) {
    union { float f; unsigned u; } a, b; a.f = f0; b.f = f1;
#if __has_builtin(__builtin_amdgcn_perm)
    return __builtin_amdgcn_perm(b.u, a.u, 0x07060302u);
#else
    return (b.u & 0xFFFF0000u) | (a.u >> 16);
#endif
}

// ---------------- fp8 e4m3 helpers ----------------
#if __has_builtin(__builtin_amdgcn_cvt_pk_fp8_f32) && __has_builtin(__builtin_amdgcn_cvt_pk_f32_fp8)
#define FP8_HW 1
#else
#define FP8_HW 0
#endif

__device__ __forceinline__ unsigned fp8enc_sw(float f) {
    union { float f; unsigned u; } v; v.f = f;
    unsigned sign = v.u >> 31;
    float a = fabsf(f);
    if (a >= 448.0f) return (sign << 7) | 0x7E;
    if (a < 0.0009765625f) return sign << 7;
    unsigned u = v.u & 0x7FFFFFFFu;
    u += 0x7FFFFu + ((u >> 20) & 1u);
    int e2 = (int)(u >> 23) - 127;
    if (e2 < -6) {
        int m = (int)(a * 512.0f + 0.5f); if (m > 7) m = 7;
        return (sign << 7) | (unsigned)m;
    }
    if (e2 > 8) return (sign << 7) | 0x7E;
    unsigned mant = (u >> 20) & 7u;
    return (sign << 7) | ((unsigned)(e2 + 7) << 3) | mant;
}
__device__ __forceinline__ float fp8dec_sw(unsigned b) {
    unsigned s = b >> 7, e = (b >> 3) & 0xF, m = b & 7;
    float v;
    if (e == 0) v = (float)m * 0.001953125f;
    else { union { unsigned u; float f; } x; x.u = ((e + 120u) << 23) | (m << 20); v = x.f; }
    return s ? -v : v;
}

__device__ __forceinline__ unsigned char f2fp8(float f) {
#if FP8_HW
    return (unsigned char)(__builtin_amdgcn_cvt_pk_fp8_f32(f, 0.f, 0, false) & 0xFF);
#else
    return (unsigned char)fp8enc_sw(f);
#endif
}
// packed accumulate: 2 cvt + 2 pk_add per 4 features
__device__ __forceinline__ void fp8x4_acc2(unsigned w, f32x2& a01, f32x2& a23) {
#if FP8_HW
    a01 += __builtin_amdgcn_cvt_pk_f32_fp8((int)w, false);
    a23 += __builtin_amdgcn_cvt_pk_f32_fp8((int)w, true);
#else
    a01[0] += fp8dec_sw(w & 0xFF); a01[1] += fp8dec_sw((w >> 8) & 0xFF);
    a23[0] += fp8dec_sw((w >> 16) & 0xFF); a23[1] += fp8dec_sw(w >> 24);
#endif
}

// ---------------- bucketed CSR build ----------------
// P1 also performs all weight conversions (independent work, saves one launch)
__global__ void bucket_hist(const int* __restrict__ dst, int e, int* __restrict__ hist,
                            const float* __restrict__ W1, ushort* __restrict__ W1t,
                            const float* __restrict__ W2, unsigned char* __restrict__ W2t,
                            const float* __restrict__ W3, unsigned char* __restrict__ W3t) {
    __shared__ int h[NB];
    const int b = blockIdx.x, t = threadIdx.x;
    for (int j = t; j < NB; j += 256) h[j] = 0;
    __syncthreads();
    const int lo = b * CHUNK;
    int hi = lo + CHUNK; if (hi > e) hi = e;
    for (int i = lo + t; i < hi; i += 256)
        atomicAdd(&h[dst[i] >> 8], 1);
    // weight conversion interleaved (independent)
    {
        const int stride = PB * 256;
        for (int idx = b * 256 + t; idx < 256 * 512 + 64 * 256 + 16 * 64; idx += stride) {
            if (idx < 256 * 512) {
                int nn = idx / 512, k = idx % 512;
                W1t[idx] = f2bf(W1[(size_t)k * 256 + nn]);
            } else if (idx < 256 * 512 + 64 * 256) {
                int r = idx - 256 * 512;
                int nn = r / 256, k = r % 256;
                W2t[r] = f2fp8(W2[(size_t)k * 64 + nn]);
            } else {
                int r = idx - 256 * 512 - 64 * 256;
                int nn = r / 64, k = r % 64;
                W3t[r] = (nn < 10) ? f2fp8(W3[(size_t)k * 10 + nn]) : (unsigned char)0;
            }
        }
    }
    __syncthreads();
    for (int j = t; j < NB; j += 256) hist[b * NB + j] = h[j];
}

__global__ void scan_buckets(int* __restrict__ hist, int* __restrict__ btotal) {
    __shared__ int s[256];
    const int j = blockIdx.x, t = threadIdx.x;
    int v0 = hist[(2 * t) * NB + j];
    int v1 = hist[(2 * t + 1) * NB + j];
    int p = v0 + v1;
    s[t] = p;
    __syncthreads();
    for (int off = 1; off < 256; off <<= 1) {
        int u = (t >= off) ? s[t - off] : 0;
        __syncthreads();
        s[t] += u;
        __syncthreads();
    }
    int excl = s[t] - p;
    hist[(2 * t) * NB + j] = excl;
    hist[(2 * t + 1) * NB + j] = excl + v0;
    if (t == 255) btotal[j] = s[255];
}

__global__ void scan_btotal(const int* __restrict__ btotal, int* __restrict__ bstart, int e) {
    __shared__ int s[512];
    const int t = threadIdx.x;
    int v = (t < NB) ? btotal[t] : 0;
    s[t] = v;
    __syncthreads();
    for (int off = 1; off < 512; off <<= 1) {
        int u = (t >= off) ? s[t - off] : 0;
        __syncthreads();
        s[t] += u;
        __syncthreads();
    }
    if (t < NB) bstart[t] = s[t] - v;
    if (t == 0) bstart[NB] = e;
}

__global__ void bucket_scatter(const int* __restrict__ src, const int* __restrict__ dst, int e,
                               const int* __restrict__ hist, const int* __restrict__ bstart,
                               unsigned* __restrict__ bucketed) {
    __shared__ int off[NB];
    const int b = blockIdx.x, t = threadIdx.x;
    for (int j = t; j < NB; j += 256) off[j] = bstart[j] + hist[b * NB + j];
    __syncthreads();
    const int lo = b * CHUNK;
    int hi = lo + CHUNK; if (hi > e) hi = e;
    for (int i = lo + t; i < hi; i += 256) {
        int d = dst[i];
        int j = d >> 8;
        int p = atomicAdd(&off[j], 1);
        bucketed[p] = (unsigned)src[i] | ((unsigned)(d & 255) << 24);
    }
}

// fused: histogram + within-bucket scan -> dinv/rowptr, then CSR fill (incl. self loops)
__global__ void bucket_finalize(const unsigned* __restrict__ bucketed, const int* __restrict__ bstart,
                                float* __restrict__ dinv, int* __restrict__ rowptr,
                                int* __restrict__ esrc, int n, int e) {
    __shared__ int h[256];
    __shared__ int s[256];
    __shared__ int rp[256];
    const int j = blockIdx.x, t = threadIdx.x;
    h[t] = 0;
    __syncthreads();
    const int lo = bstart[j], hi = bstart[j + 1];
    for (int i = lo + t; i < hi; i += 256)
        atomicAdd(&h[bucketed[i] >> 24], 1);
    __syncthreads();
    const int c = h[t] + 1;  // deg + self loop
    s[t] = c;
    __syncthreads();
    for (int off = 1; off < 256; off <<= 1) {
        int u = (t >= off) ? s[t - off] : 0;
        __syncthreads();
        s[t] += u;
        __syncthreads();
    }
    const int excl = s[t] - c;
    const int base = j << 8;
    const int node = base + t;
    const int myrp = bstart[j] + base + excl;
    rp[t] = myrp;
    if (node < n) {
        dinv[node] = rsqrtf((float)c);
        rowptr[node] = myrp;
        esrc[myrp] = node;  // self loop at slot 0
    }
    if (j == 0 && t == 0) rowptr[n] = e + n;
    h[t] = 0;
    __syncthreads();
    for (int i = lo + t; i < hi; i += 256) {
        unsigned ed = bucketed[i];
        int l = ed >> 24;
        int off = atomicAdd(&h[l], 1);
        esrc[rp[l] + 1 + off] = (int)(ed & 0xFFFFFFu);
    }
}

// ---------------- GEMM layer 1: f32 A staged directly (swizzled), fp8 output ----------------
template <int BM, int BN, int BK, int WM, int WN>
__launch_bounds__(WM* WN * 64)
__global__ void gemm_f32a(const float* __restrict__ A, const ushort* __restrict__ Bt,
                          const float* __restrict__ dinv, unsigned char* __restrict__ Cout,
                          int M, int N, int K) {
    constexpr int NT = WM * WN * 64;
    __shared__ __align__(16) float Asf[BM][BK];
    __shared__ __align__(16) ushort Bs[BN][BK];
    const int tid = threadIdx.x;
    const int wid = tid >> 6, lane = tid & 63;
    const int wr = wid / WN, wc = wid % WN;
    constexpr int TM = BM / WM, TN = BN / WN;
    constexpr int FM = TM / 16, FN = TN / 16;
    const int m0 = blockIdx.y * BM, n0 = blockIdx.x * BN;
    const int ln = lane & 15, ks4 = (lane >> 4) * 2;

    f32x4 acc[FM][FN] = {};

    constexpr int CPRA = BK / 4;
    constexpr int ACH = BM * CPRA;
    constexpr int CPRB = BK / 8;
    constexpr int BCH = BN * CPRB;

    for (int k0 = 0; k0 < K; k0 += BK) {
        #pragma unroll
        for (int it = 0; it < ACH / NT; ++it) {
            int c = it * NT + tid;
            int row = c >> 3, chs = c & 7;
            int gch = chs ^ (row & 7);
            int gm = m0 + row; if (gm >= M) gm = M - 1;
            const float* gp = &A[(size_t)gm * K + k0 + gch * 4];
            __builtin_amdgcn_global_load_lds(
                (const __attribute__((address_space(1))) void*)gp,
                (__attribute__((address_space(3))) void*)((char*)&Asf[0][0] + c * 16),
                16, 0, 0);
        }
        #pragma unroll
        for (int it = 0; it < BCH / NT; ++it) {
            int c = it * NT + tid;
            int row = c / CPRB, ch = c % CPRB;
            const ushort* gp = &Bt[(size_t)(n0 + row) * K + k0 + ch * 8];
            __builtin_amdgcn_global_load_lds(
                (const __attribute__((address_space(1))) void*)gp,
                (__attribute__((address_space(3))) void*)((char*)&Bs[0][0] + c * 16),
                16, 0, 0);
        }
        __syncthreads();

        bf16x8 af[FM], bfr[FN];
        #pragma unroll
        for (int mi = 0; mi < FM; ++mi) {
            int r = wr * TM + mi * 16 + ln;
            const char* rowp = (const char*)&Asf[0][0] + r * (BK * 4);
            float4 a0 = *(const float4*)(rowp + ((ks4 ^ (r & 7)) * 16));
            float4 a1 = *(const float4*)(rowp + (((ks4 + 1) ^ (r & 7)) * 16));
            union { unsigned w[4]; bf16x8 v; } u;
            u.w[0] = pack_bf2(a0.x, a0.y);
            u.w[1] = pack_bf2(a0.z, a0.w);
            u.w[2] = pack_bf2(a1.x, a1.y);
            u.w[3] = pack_bf2(a1.z, a1.w);
            af[mi] = u.v;
        }
        const int ks = (lane >> 4) * 8;
        #pragma unroll
        for (int nj = 0; nj < FN; ++nj)
            bfr[nj] = *(const bf16x8*)&Bs[wc * TN + nj * 16 + ln][ks];
        #pragma unroll
        for (int mi = 0; mi < FM; ++mi)
            #pragma unroll
            for (int nj = 0; nj < FN; ++nj)
                acc[mi][nj] = __builtin_amdgcn_mfma_f32_16x16x32_bf16(af[mi], bfr[nj], acc[mi][nj], 0, 0, 0);
        __syncthreads();
    }

    const int rbase = (lane >> 4) * 4;
    #pragma unroll
    for (int mi = 0; mi < FM; ++mi) {
        #pragma unroll
        for (int r = 0; r < 4; ++r) {
            int gm = m0 + wr * TM + mi * 16 + rbase + r;
            if (gm >= M) continue;
            float d = dinv[gm];
            #pragma unroll
            for (int nj = 0; nj < FN; ++nj) {
                int gn = n0 + wc * TN + nj * 16 + ln;
                Cout[(size_t)gm * N + gn] = f2fp8(acc[mi][nj][r] * d);
            }
        }
    }
}

// ---------------- fp8 MFMA GEMM (layers 2-3): A fp8 [M][K], Bt fp8 [N][K] ----------------
// OUTK: 0 = bf16, 2 = fp8
template <int BM, int BN, int BK, int WM, int WN, int OUTK>
__launch_bounds__(WM* WN * 64)
__global__ void gemm_fp8(const unsigned char* __restrict__ A, const unsigned char* __restrict__ Bt,
                         const float* __restrict__ dinv, void* __restrict__ Cout,
                         int M, int N, int K) {
    constexpr int NT = WM * WN * 64;
    __shared__ __align__(16) unsigned char As[BM][BK];
    __shared__ __align__(16) unsigned char Bs[BN][BK];
    const int tid = threadIdx.x;
    const int wid = tid >> 6, lane = tid & 63;
    const int wr = wid / WN, wc = wid % WN;
    constexpr int TM = BM / WM, TN = BN / WN;
    constexpr int FM = TM / 16, FN = TN / 16;
    const int m0 = blockIdx.y * BM, n0 = blockIdx.x * BN;
    const int ln = lane & 15;

    f32x4 acc[FM][FN] = {};

    constexpr int CPR = BK / 16;
    constexpr int ACH = BM * CPR;
    constexpr int BCH = BN * CPR;

    for (int k0 = 0; k0 < K; k0 += BK) {
        #pragma unroll
        for (int it = 0; it < (ACH + NT - 1) / NT; ++it) {
            int c = it * NT + tid;
            if ((ACH % NT == 0) || (c < ACH)) {
                int row = c / CPR, ch = c % CPR;
                int gm = m0 + row; if (gm >= M) gm = M - 1;
                const unsigned char* gp = &A[(size_t)gm * K + k0 + ch * 16];
                __builtin_amdgcn_global_load_lds(
                    (const __attribute__((address_space(1))) void*)gp,
                    (__attribute__((address_space(3))) void*)((char*)&As[0][0] + c * 16),
                    16, 0, 0);
            }
        }
        #pragma unroll
        for (int it = 0; it < (BCH + NT - 1) / NT; ++it) {
            int c = it * NT + tid;
            if ((BCH % NT == 0) || (c < BCH)) {
                int row = c / CPR, ch = c % CPR;
                const unsigned char* gp = &Bt[(size_t)(n0 + row) * K + k0 + ch * 16];
                __builtin_amdgcn_global_load_lds(
                    (const __attribute__((address_space(1))) void*)gp,
                    (__attribute__((address_space(3))) void*)((char*)&Bs[0][0] + c * 16),
                    16, 0, 0);
            }
        }
        __syncthreads();

        long af[FM], bfr[FN];
        #pragma unroll
        for (int mi = 0; mi < FM; ++mi)
            af[mi] = ((const long*)&As[0][0])[(wr * TM + mi * 16 + ln) * (BK / 8) + (lane >> 4)];
        #pragma unroll
        for (int nj = 0; nj < FN; ++nj)
            bfr[nj] = ((const long*)&Bs[0][0])[(wc * TN + nj * 16 + ln) * (BK / 8) + (lane >> 4)];
        #pragma unroll
        for (int mi = 0; mi < FM; ++mi)
            #pragma unroll
            for (int nj = 0; nj < FN; ++nj)
                acc[mi][nj] = __builtin_amdgcn_mfma_f32_16x16x32_fp8_fp8(af[mi], bfr[nj], acc[mi][nj], 0, 0, 0);
        __syncthreads();
    }

    const int rbase = (lane >> 4) * 4;
    #pragma unroll
    for (int mi = 0; mi < FM; ++mi) {
        #pragma unroll
        for (int r = 0; r < 4; ++r) {
            int gm = m0 + wr * TM + mi * 16 + rbase + r;
            if (gm >= M) continue;
            float d = dinv[gm];
            #pragma unroll
            for (int nj = 0; nj < FN; ++nj) {
                int gn = n0 + wc * TN + nj * 16 + ln;
                float v = acc[mi][nj][r] * d;
                if (OUTK == 0) ((ushort*)Cout)[(size_t)gm * N + gn] = f2bf(v);
                else           ((unsigned char*)Cout)[(size_t)gm * N + gn] = f2fp8(v);
            }
        }
    }
}

// ---------------- layer-1 aggregation: fp8 rows (256 B), wave/node, 8-edge ILP, fp8 out ----------------
__global__ void agg1_fp8(const unsigned* __restrict__ h, const int* __restrict__ rowptr,
                         const int* __restrict__ esrc, const float* __restrict__ dinv,
                         const float* __restrict__ bias, unsigned char* __restrict__ out, int n) {
    const int wid = threadIdx.x >> 6, lane = threadIdx.x & 63;
    const int i = blockIdx.x * 4 + wid;
    if (i >= n) return;
    const int lo = rowptr[i], hi = rowptr[i + 1];
    f32x2 a01 = {0.f, 0.f}, a23 = {0.f, 0.f};
    int e = lo;
    for (; e + 7 < hi; e += 8) {
        int s[8];
        unsigned w[8];
        #pragma unroll
        for (int q = 0; q < 8; ++q) s[q] = esrc[e + q];
        #pragma unroll
        for (int q = 0; q < 8; ++q) w[q] = h[(size_t)s[q] * 64 + lane];
        #pragma unroll
        for (int q = 0; q < 8; ++q) fp8x4_acc2(w[q], a01, a23);
    }
    for (; e < hi; ++e)
        fp8x4_acc2(h[(size_t)esrc[e] * 64 + lane], a01, a23);

    float d = dinv[i];
    const int f0 = lane * 4;
    float4 b = *(const float4*)&bias[f0];
    uchar4 o;
    o.x = f2fp8(fmaxf(a01[0] * d + b.x, 0.f));
    o.y = f2fp8(fmaxf(a01[1] * d + b.y, 0.f));
    o.z = f2fp8(fmaxf(a23[0] * d + b.z, 0.f));
    o.w = f2fp8(fmaxf(a23[1] * d + b.w, 0.f));
    *(uchar4*)&out[(size_t)i * 256 + f0] = o;
}

// ---------------- layer-2 aggregation: fp8 rows (64 B), 16 lanes/node, 8-edge ILP ----------------
__global__ void agg2_fp8(const unsigned* __restrict__ h, const int* __restrict__ rowptr,
                         const int* __restrict__ esrc, const float* __restrict__ dinv,
                         const float* __restrict__ bias, unsigned char* __restrict__ out, int n) {
    const int g = threadIdx.x >> 4, j = threadIdx.x & 15;
    const int i = blockIdx.x * 16 + g;
    if (i >= n) return;
    const int lo = rowptr[i], hi = rowptr[i + 1];
    f32x2 a01 = {0.f, 0.f}, a23 = {0.f, 0.f};
    int e = lo;
    for (; e + 7 < hi; e += 8) {
        int s[8];
        unsigned w[8];
        #pragma unroll
        for (int q = 0; q < 8; ++q) s[q] = esrc[e + q];
        #pragma unroll
        for (int q = 0; q < 8; ++q) w[q] = h[(size_t)s[q] * 16 + j];
        #pragma unroll
        for (int q = 0; q < 8; ++q) fp8x4_acc2(w[q], a01, a23);
    }
    for (; e < hi; ++e)
        fp8x4_acc2(h[(size_t)esrc[e] * 16 + j], a01, a23);

    float d = dinv[i];
    const int f0 = j * 4;
    float4 b = *(const float4*)&bias[f0];
    uchar4 o;
    o.x = f2fp8(fmaxf(a01[0] * d + b.x, 0.f));
    o.y = f2fp8(fmaxf(a01[1] * d + b.y, 0.f));
    o.z = f2fp8(fmaxf(a23[0] * d + b.z, 0.f));
    o.w = f2fp8(fmaxf(a23[1] * d + b.w, 0.f));
    *(uchar4*)&out[(size_t)i * 64 + f0] = o;
}

// ---------------- layer-3: bf16 rows (32 B), 8 lanes/node, fused log_softmax ----------------
__global__ void agg3_logsoftmax(const ushort* __restrict__ h3, const int* __restrict__ rowptr,
                                const int* __restrict__ esrc, const float* __restrict__ dinv,
                                const float* __restrict__ bias, float* __restrict__ out, int n) {
    const int g = threadIdx.x >> 3, j = threadIdx.x & 7;
    const int i = blockIdx.x * 32 + g;
    if (i >= n) return;
    const int lo = rowptr[i], hi = rowptr[i + 1];
    float a0 = 0.f, a1 = 0.f;
    int e = lo;
    for (; e + 3 < hi; e += 4) {
        int s0 = esrc[e], s1 = esrc[e + 1], s2 = esrc[e + 2], s3 = esrc[e + 3];
        unsigned w0 = *(const unsigned*)&h3[(size_t)s0 * 16 + 2 * j];
        unsigned w1 = *(const unsigned*)&h3[(size_t)s1 * 16 + 2 * j];
        unsigned w2 = *(const unsigned*)&h3[(size_t)s2 * 16 + 2 * j];
        unsigned w3 = *(const unsigned*)&h3[(size_t)s3 * 16 + 2 * j];
        a0 += bf2f((ushort)(w0 & 0xFFFF)) + bf2f((ushort)(w1 & 0xFFFF))
            + bf2f((ushort)(w2 & 0xFFFF)) + bf2f((ushort)(w3 & 0xFFFF));
        a1 += bf2f((ushort)(w0 >> 16)) + bf2f((ushort)(w1 >> 16))
            + bf2f((ushort)(w2 >> 16)) + bf2f((ushort)(w3 >> 16));
    }
    for (; e < hi; ++e) {
        unsigned w = *(const unsigned*)&h3[(size_t)esrc[e] * 16 + 2 * j];
        a0 += bf2f((ushort)(w & 0xFFFF));
        a1 += bf2f((ushort)(w >> 16));
    }
    const int f0 = 2 * j;
    float d = dinv[i];
    float v0 = (f0 < 10) ? (a0 * d + bias[f0]) : -INFINITY;
    float v1 = (f0 + 1 < 10) ? (a1 * d + bias[f0 + 1]) : -INFINITY;
    float m = fmaxf(v0, v1);
    #pragma unroll
    for (int off = 1; off < 8; off <<= 1) m = fmaxf(m, __shfl_xor(m, off, 8));
    float ex = ((f0 < 10) ? expf(v0 - m) : 0.f) + ((f0 + 1 < 10) ? expf(v1 - m) : 0.f);
    #pragma unroll
    for (int off = 1; off < 8; off <<= 1) ex += __shfl_xor(ex, off, 8);
    float ls = logf(ex);
    if (f0 < 10)     out[(size_t)i * 10 + f0] = v0 - m - ls;
    if (f0 + 1 < 10) out[(size_t)i * 10 + f0 + 1] = v1 - m - ls;
}

extern "C" void kernel_launch(void* const* d_in, const int* in_sizes, int n_in,
                              void* d_out, int out_size, void* d_ws, size_t ws_size,
                              hipStream_t stream) {
    const int N = NNODES, E = NEDGES;
    const float* x  = (const float*)d_in[0];
    const int*   ei = (const int*)d_in[1];
    const float* W1 = (const float*)d_in[2];
    const float* b1 = (const float*)d_in[3];
    const float* W2 = (const float*)d_in[4];
    const float* b2 = (const float*)d_in[5];
    const float* W3 = (const float*)d_in[6];
    const float* b3 = (const float*)d_in[7];
    float* out = (float*)d_out;
    const int* src = ei;
    const int* dst = ei + E;

    char* ws = (char*)d_ws;
    size_t off = 0;
    auto alloc = [&](size_t bytes) -> void* {
        void* p = ws + off;
        off = (off + bytes + 255) & ~(size_t)255;
        return p;
    };
    float* dinv   = (float*)alloc((size_t)N * 4);
    int*   rowptr = (int*)alloc((size_t)(N + 1) * 4);
    int*   btotal = (int*)alloc((size_t)NB * 4);
    int*   bstart = (int*)alloc((size_t)(NB + 1) * 4);
    int*   esrc   = (int*)alloc((size_t)(E + N) * 4);
    ushort* W1t   = (ushort*)alloc((size_t)256 * 512 * 2);
    unsigned char* W2t8 = (unsigned char*)alloc((size_t)64 * 256);
    unsigned char* W3t8 = (unsigned char*)alloc((size_t)16 * 64);
    ushort* h3b   = (ushort*)alloc((size_t)N * 16 * 2);
    ushort* buf1  = (ushort*)alloc((size_t)N * 256 * 2);
    ushort* buf2  = (ushort*)alloc((size_t)N * 256 * 2);
    int*   hist   = (int*)buf1;                    // dead before gemm1 writes buf1
    unsigned* bucketed = (unsigned*)buf2;          // dead before agg1 writes buf2
    unsigned char* h1fp8 = (unsigned char*)buf1;   // gemm1 out [N][256B]
    unsigned char* a1fp8 = (unsigned char*)buf2;   // agg1 out  [N][256B] (bucketed dead)
    unsigned char* h2fp8 = (unsigned char*)buf1;   // gemm2 out [N][64B]  (h1fp8 dead)
    unsigned char* a2fp8 = (unsigned char*)buf2;   // agg2 out  [N][64B]  (a1fp8 dead)

    const int T = 256;
    // bucketed CSR build (weight conversions folded into bucket_hist)
    bucket_hist<<<PB, T, 0, stream>>>(dst, E, hist, W1, W1t, W2, W2t8, W3, W3t8);
    scan_buckets<<<NB, T, 0, stream>>>(hist, btotal);
    scan_btotal<<<1, 512, 0, stream>>>(btotal, bstart, E);
    bucket_scatter<<<PB, T, 0, stream>>>(src, dst, E, hist, bstart, bucketed);
    bucket_finalize<<<NB, T, 0, stream>>>(bucketed, bstart, dinv, rowptr, esrc, N, E);

    const int MB = (N + 127) / 128;

    // Layer 1: f32-A gemm -> fp8 h1 ; fp8 gather -> fp8 a1 [N][256B]
    gemm_f32a<128, 256, 32, 2, 4><<<dim3(1, MB), 512, 0, stream>>>(x, W1t, dinv, h1fp8, N, 256, 512);
    agg1_fp8<<<(N + 3) / 4, 256, 0, stream>>>((const unsigned*)h1fp8, rowptr, esrc, dinv, b1, a1fp8, N);

    // Layer 2: fp8 gemm -> fp8 h2 [N][64B] ; fp8 gather -> fp8 a2 [N][64B]
    gemm_fp8<128, 64, 32, 2, 2, 2><<<dim3(1, MB), 256, 0, stream>>>(a1fp8, W2t8, dinv, h2fp8, N, 64, 256);
    agg2_fp8<<<(N + 15) / 16, 256, 0, stream>>>((const unsigned*)h2fp8, rowptr, esrc, dinv, b2, a2fp8, N);

    // Layer 3: fp8 gemm -> bf16 h3 [N][16] ; gather + fused log_softmax -> out
    gemm_fp8<128, 16, 32, 4, 1, 0><<<dim3(1, MB), 256, 0, stream>>>(a2fp8, W3t8, dinv, h3b, N, 16, 64);
    agg3_logsoftmax<<<(N + 31) / 32, 256, 0, stream>>>(h3b, rowptr, esrc, dinv, b3, out, N);
}